// Round 2
// baseline (833.283 us; speedup 1.0000x reference)
//
#include <hip/hip_runtime.h>
#include <hip/hip_bf16.h>
#include <math.h>

#define BB 16
#define NN 512
#define DIN 128
#define DM 256
#define NH 8
#define DH 32
#define FF 1024
#define DOUT 128
#define NHOP 258
#define NEDGE 27
#define ROWS (BB*NN)   // 8192
#define QHE_S 296      // qhe row stride (ushorts): qh 0..257, qec at 264..290; becomes vha bins after k_score

typedef short short8 __attribute__((ext_vector_type(8)));
typedef float f32x4 __attribute__((ext_vector_type(4)));

static __device__ __forceinline__ float bf2f(unsigned short u) {
    union { float f; unsigned int i; } c; c.i = ((unsigned int)u) << 16; return c.f;
}
static __device__ __forceinline__ short f2bs(float f) {
    __hip_bfloat16 h = __float2bfloat16(f);
    return *reinterpret_cast<short*>(&h);
}

// ---------------- layernorm: one wave per row, float4 + shuffle ----------------
__global__ __launch_bounds__(256) void k_ln(const float* __restrict__ in, const float* __restrict__ g,
                                            const float* __restrict__ bta, float* __restrict__ out) {
    int row = blockIdx.x * 4 + (threadIdx.x >> 6);
    int l = threadIdx.x & 63;
    float4 xv = ((const float4*)(in + (size_t)row*DM))[l];
    float s = xv.x + xv.y + xv.z + xv.w;
    #pragma unroll
    for (int o = 32; o > 0; o >>= 1) s += __shfl_xor(s, o, 64);
    float mean = s * (1.0f/DM);
    float dx = xv.x-mean, dy = xv.y-mean, dz = xv.z-mean, dw = xv.w-mean;
    float vs = dx*dx + dy*dy + dz*dz + dw*dw;
    #pragma unroll
    for (int o = 32; o > 0; o >>= 1) vs += __shfl_xor(vs, o, 64);
    float r = rsqrtf(vs * (1.0f/DM) + 1e-5f);
    float4 gg = ((const float4*)g)[l];
    float4 bb = ((const float4*)bta)[l];
    float4 ov; ov.x = dx*r*gg.x+bb.x; ov.y = dy*r*gg.y+bb.y; ov.z = dz*r*gg.z+bb.z; ov.w = dw*r*gg.w+bb.w;
    ((float4*)(out + (size_t)row*DM))[l] = ov;
}

// ---------------- MFMA bf16 GEMM: 64x64 tile, fp32 in, bf16 staging ----------------
// QKV=0: fp32 out (ACT=gelu, RES=+=). QKV=1: bf16 out [B,H,N,DH]. QKV=2: bf16 out transposed [B,H,DH,N].
template<int K, int N, int ACT, int RES, int QKV>
__global__ __launch_bounds__(256) void k_mgemm(const float* __restrict__ A, const float* __restrict__ W,
                                               const float* __restrict__ bias, void* __restrict__ outv) {
    __shared__ __align__(16) short As[64][40];   // [m][k] bf16
    __shared__ __align__(16) short Bs[64][40];   // [n][k] bf16
    int r0 = blockIdx.x * 64;
    int n0 = blockIdx.y * 64;
    int tid = threadIdx.x;
    int w = tid >> 6, l = tid & 63;

    f32x4 acc[4];
    #pragma unroll
    for (int c = 0; c < 4; ++c) acc[c] = (f32x4){0.f,0.f,0.f,0.f};

    for (int k0 = 0; k0 < K; k0 += 32) {
        __syncthreads();
        {
            int m = tid >> 2, ks = (tid & 3) * 8;
            const float* src = A + (size_t)(r0 + m)*K + k0 + ks;
            float4 f0 = *(const float4*)src;
            float4 f1 = *(const float4*)(src + 4);
            short8 pk;
            pk[0]=f2bs(f0.x); pk[1]=f2bs(f0.y); pk[2]=f2bs(f0.z); pk[3]=f2bs(f0.w);
            pk[4]=f2bs(f1.x); pk[5]=f2bs(f1.y); pk[6]=f2bs(f1.z); pk[7]=f2bs(f1.w);
            *(short8*)&As[m][ks] = pk;
        }
        {
            int n = tid & 63, kg = tid >> 6;
            const float* wp = W + (size_t)(k0 + kg*8)*N + n0 + n;
            short8 pk;
            #pragma unroll
            for (int j = 0; j < 8; ++j) pk[j] = f2bs(wp[(size_t)j*N]);
            *(short8*)&Bs[n][kg*8] = pk;
        }
        __syncthreads();
        short8 af = *(short8*)&As[w*16 + (l & 15)][(l >> 4)*8];
        #pragma unroll
        for (int c = 0; c < 4; ++c) {
            short8 bf = *(short8*)&Bs[c*16 + (l & 15)][(l >> 4)*8];
            acc[c] = __builtin_amdgcn_mfma_f32_16x16x32_bf16(af, bf, acc[c], 0, 0, 0);
        }
    }

    int quad = l >> 4;
    #pragma unroll
    for (int c = 0; c < 4; ++c) {
        int col = n0 + c*16 + (l & 15);
        float bv = bias[col];
        #pragma unroll
        for (int reg = 0; reg < 4; ++reg) {
            int row = r0 + w*16 + quad*4 + reg;
            float val = acc[c][reg] + bv;
            if (ACT) val = 0.5f * val * (1.0f + erff(val * 0.70710678118654752f));
            if (QKV == 1) {
                unsigned short* out = (unsigned short*)outv;
                int b = row >> 9, n = row & (NN-1);
                int hh = col >> 5, d = col & (DH-1);
                out[(size_t)((b*NH + hh)*NN + n)*DH + d] = (unsigned short)f2bs(val);
            } else if (QKV == 2) {
                unsigned short* out = (unsigned short*)outv;
                int b = row >> 9, n = row & (NN-1);
                int hh = col >> 5, d = col & (DH-1);
                out[(size_t)((b*NH + hh)*DH + d)*NN + n] = (unsigned short)f2bs(val);
            } else if (RES) {
                ((float*)outv)[(size_t)row*N + col] += val;
            } else {
                ((float*)outv)[(size_t)row*N + col] = val;
            }
        }
    }
}

// ---------------- k_prep: build w2[8][304][64] bf16 and vhve_d[8][32][320] bf16 ----------------
__global__ __launch_bounds__(256) void k_prep(const float* __restrict__ q_hop, const float* __restrict__ q_edge,
                                              const float* __restrict__ k_edge, const float* __restrict__ v_hop,
                                              const float* __restrict__ v_edge,
                                              unsigned short* __restrict__ w2, unsigned short* __restrict__ vhve_d) {
    int h = blockIdx.x;
    int tid = threadIdx.x;
    for (int idx = tid; idx < 304*64; idx += 256) {
        int n = idx >> 6, kk = idx & 63;
        float val = 0.f;
        if (n < NHOP && kk < 32) val = q_hop[(size_t)n*DM + h*DH + kk];
        else if (n >= 264 && n < 264 + NEDGE) {
            int e = n - 264;
            val = (kk < 32) ? q_edge[(size_t)e*DM + h*DH + kk]
                            : k_edge[(size_t)e*DM + h*DH + (kk - 32)];
        }
        w2[((size_t)h*304 + n)*64 + kk] = (unsigned short)f2bs(val);
    }
    for (int idx = tid; idx < 32*320; idx += 256) {
        int d = idx / 320, kk = idx - d*320;
        float val = 0.f;
        if (kk < NHOP) val = v_hop[(size_t)kk*DM + h*DH + d];
        else if (kk >= 264 && kk < 264 + NEDGE) val = v_edge[(size_t)(kk-264)*DM + h*DH + d];
        vhve_d[((size_t)h*32 + d)*320 + kk] = (unsigned short)f2bs(val);
    }
}

// ---------------- k_kht2: kht[bh][m][j] = Kh[h][m][:] @ k_bf[bh][j][:]  via MFMA ----------------
__global__ __launch_bounds__(256) void k_kht2(const unsigned short* __restrict__ k_bf,
                                              const float* __restrict__ k_hop,
                                              unsigned short* __restrict__ kht) {
    int bh = blockIdx.x;
    int hh = bh & (NH-1);
    int r0 = blockIdx.y * 64;   // m tile
    int tid = threadIdx.x;
    int w = tid >> 6, l = tid & 63;
    int quad = l >> 4, lr = l & 15;

    int m = r0 + w*16 + lr;
    int mc = m < NHOP ? m : NHOP-1;
    const float* ar = k_hop + (size_t)mc*DM + hh*DH + quad*8;
    float4 a0 = *(const float4*)ar;
    float4 a1 = *(const float4*)(ar + 4);
    short8 af;
    af[0]=f2bs(a0.x); af[1]=f2bs(a0.y); af[2]=f2bs(a0.z); af[3]=f2bs(a0.w);
    af[4]=f2bs(a1.x); af[5]=f2bs(a1.y); af[6]=f2bs(a1.z); af[7]=f2bs(a1.w);

    for (int ct = 0; ct < 32; ++ct) {
        short8 bf = *(const short8*)(k_bf + ((size_t)bh*NN + ct*16 + lr)*DH + quad*8);
        f32x4 acc = (f32x4){0.f,0.f,0.f,0.f};
        acc = __builtin_amdgcn_mfma_f32_16x16x32_bf16(af, bf, acc, 0, 0, 0);
        #pragma unroll
        for (int reg = 0; reg < 4; ++reg) {
            int m2 = r0 + w*16 + quad*4 + reg;
            if (m2 < NHOP)
                kht[((size_t)bh*NHOP + m2)*NN + ct*16 + lr] = (unsigned short)f2bs(acc[reg]);
        }
    }
}

// ---------------- k_qhe2: qhe rows via MFMA; A = [q_bf | k_bf] (K=64), B^T = w2 ----------------
__global__ __launch_bounds__(256) void k_qhe2(const unsigned short* __restrict__ q_bf,
                                              const unsigned short* __restrict__ k_bf,
                                              const unsigned short* __restrict__ w2,
                                              unsigned short* __restrict__ qhe) {
    int bh = blockIdx.x;
    int hh = bh & (NH-1);
    int r0 = blockIdx.y * 64;
    int tid = threadIdx.x;
    int w = tid >> 6, l = tid & 63;
    int quad = l >> 4, lr = l & 15;

    int row0 = r0 + w*16 + lr;
    short8 af0 = *(const short8*)(q_bf + ((size_t)bh*NN + row0)*DH + quad*8);
    short8 af1 = *(const short8*)(k_bf + ((size_t)bh*NN + row0)*DH + quad*8);

    const unsigned short* w2h = w2 + (size_t)hh*304*64;
    for (int ct = 0; ct < 19; ++ct) {
        int col = ct*16 + lr;
        short8 b0 = *(const short8*)(w2h + (size_t)col*64 + quad*8);
        short8 b1 = *(const short8*)(w2h + (size_t)col*64 + 32 + quad*8);
        f32x4 acc = (f32x4){0.f,0.f,0.f,0.f};
        acc = __builtin_amdgcn_mfma_f32_16x16x32_bf16(af0, b0, acc, 0, 0, 0);
        acc = __builtin_amdgcn_mfma_f32_16x16x32_bf16(af1, b1, acc, 0, 0, 0);
        if (col < QHE_S) {
            #pragma unroll
            for (int reg = 0; reg < 4; ++reg) {
                int row = r0 + w*16 + quad*4 + reg;
                qhe[((size_t)bh*NN + row)*QHE_S + col] = (unsigned short)f2bs(acc[reg]);
            }
        }
    }
}

// ---------------- k_score: flash-style MFMA. block = (b, head, 16-row i-tile); 4 waves ----------------
// v3: r0's coalesced int4 decode into mje LDS, but bins ALIASES mje (mje dead after phase C;
//     pk codes stashed in 16 packed VGPRs during the bias-gather loop). LDS 52K -> 35.8K
//     -> 4 blocks/CU. waves_per_eu(4,4) stops the allocator squeezing to 64 regs (r1 spilled).
__global__ __launch_bounds__(256) __attribute__((amdgpu_waves_per_eu(4, 4))) void k_score(
    const unsigned short* __restrict__ q_bf, const unsigned short* __restrict__ k_bf,
    const unsigned short* __restrict__ vT_bf, const unsigned short* __restrict__ kht,
    const int* __restrict__ dist, const int* __restrict__ edge,
    const unsigned char* __restrict__ mask, unsigned short* __restrict__ qhe,
    float* __restrict__ ctx)
{
    int g = blockIdx.x;                 // 4096
    int r = g >> 3;                     // 0..511
    int b = (g & 7) + ((r >> 8) << 3);  // XCD-affine
    int rem = r & 255;
    int hh = rem >> 5;
    int i0 = (rem & 31) << 4;
    int bh = b*NH + hh;
    int tid = threadIdx.x;
    int w = tid >> 6, l = tid & 63;
    int lr = l & 15, quad = l >> 4;

    // LDS time-multiplexed layout (35840 B total):
    //   [0, 16384)   mje[16][512] u16      (phases A-C)
    //   [0, 18688)   bins[16][292] f32     (aliases mje; zeroed after C, scattered, dumped)
    //   [0,  8192)   cpart[4][16][32] f32  (aliases bins; PV partial reduce)
    //   [18688, 35328) Pl[16][520] u16
    //   [35328, 35840) red[2][4][16] f32
    __shared__ __align__(16) unsigned char smem[35840];
    unsigned short (*mje)[512] = (unsigned short(*)[512])smem;
    float (*bins)[292] = (float(*)[292])smem;
    unsigned short (*Pl)[520] = (unsigned short(*)[520])(smem + 18688);
    float (*red)[4][16] = (float(*)[4][16])(smem + 35328);
    float* cpart = (float*)smem;

    // ---- phase A: decode dist/edge (16 contiguous rows) -> mje, coalesced int4 ----
    {
        const int4* dp = (const int4*)(dist + ((size_t)b*NN + i0)*NN);
        const int4* ep = (const int4*)(edge + ((size_t)b*NN + i0)*NN);
        unsigned short* mf = &mje[0][0];
        for (int idx = tid; idx < 2048; idx += 256) {
            int4 dv = dp[idx];
            int4 ev = ep[idx];
            int m0 = dv.x > 256 ? 256 : dv.x; if (dv.x < 0) m0 = 257;
            int m1 = dv.y > 256 ? 256 : dv.y; if (dv.y < 0) m1 = 257;
            int m2 = dv.z > 256 ? 256 : dv.z; if (dv.z < 0) m2 = 257;
            int m3 = dv.w > 256 ? 256 : dv.w; if (dv.w < 0) m3 = 257;
            int e0 = ev.x > 25 ? 25 : ev.x; if (ev.x < 0) e0 = 26;
            int e1 = ev.y > 25 ? 25 : ev.y; if (ev.y < 0) e1 = 26;
            int e2 = ev.z > 25 ? 25 : ev.z; if (ev.z < 0) e2 = 26;
            int e3 = ev.w > 25 ? 25 : ev.w; if (ev.w < 0) e3 = 26;
            uint2 pk;
            pk.x = (unsigned)(m0 | (e0<<9)) | ((unsigned)(m1 | (e1<<9)) << 16);
            pk.y = (unsigned)(m2 | (e2<<9)) | ((unsigned)(m3 | (e3<<9)) << 16);
            *(uint2*)&mf[idx*4] = pk;
        }
    }
    __syncthreads();   // B1: mje ready

    // ---- phase B: QK^T via MFMA (wave w covers j in [w*128, w*128+128)) ----
    int jbase = w*128;
    short8 af = *(const short8*)(q_bf + ((size_t)bh*NN + i0 + lr)*DH + quad*8);
    f32x4 sc[8];
    #pragma unroll
    for (int ct = 0; ct < 8; ++ct) {
        short8 bfr = *(const short8*)(k_bf + ((size_t)bh*NN + jbase + ct*16 + lr)*DH + quad*8);
        f32x4 z = (f32x4){0.f,0.f,0.f,0.f};
        sc[ct] = __builtin_amdgcn_mfma_f32_16x16x32_bf16(af, bfr, z, 0, 0, 0);
    }

    // ---- phase C: bias gathers + mask; stash pk codes in 16 packed VGPRs ----
    const unsigned short* khtb = kht + (size_t)bh*NHOP*NN;
    const unsigned char* mrow = mask + (size_t)b*NN;
    const float scale = 0.17677669529663687f;
    unsigned char msk[8];
    #pragma unroll
    for (int ct = 0; ct < 8; ++ct) msk[ct] = mrow[jbase + ct*16 + lr];

    unsigned int pk2[8][2];
    #pragma unroll
    for (int ct = 0; ct < 8; ++ct) {
        int j = jbase + ct*16 + lr;
        #pragma unroll
        for (int reg = 0; reg < 4; ++reg) {
            int il = quad*4 + reg;
            unsigned int pk = mje[il][j];
            if (reg & 1) pk2[ct][reg>>1] |= pk << 16;
            else         pk2[ct][reg>>1]  = pk;
            int m = pk & 511, e = (int)(pk >> 9);
            const unsigned short* qhr = qhe + ((size_t)bh*NN + i0 + il)*QHE_S;
            float a = sc[ct][reg] + bf2f(khtb[(size_t)m*NN + j]) + bf2f(qhr[m]) + bf2f(qhr[264 + e]);
            a *= scale;
            if (msk[ct]) a = -INFINITY;
            sc[ct][reg] = a;
        }
    }

    // ---- softmax across all 512 j (cross-wave via LDS) ----
    {
        float mymax[4];
        #pragma unroll
        for (int reg = 0; reg < 4; ++reg) {
            float mx = sc[0][reg];
            #pragma unroll
            for (int ct = 1; ct < 8; ++ct) mx = fmaxf(mx, sc[ct][reg]);
            #pragma unroll
            for (int o = 1; o < 16; o <<= 1) mx = fmaxf(mx, __shfl_xor(mx, o, 16));
            mymax[reg] = mx;
        }
        if (lr == 0) {
            #pragma unroll
            for (int reg = 0; reg < 4; ++reg) red[0][w][quad*4 + reg] = mymax[reg];
        }
        __syncthreads();   // B2: red[0] ready; ALL mje reads done -> bins may overwrite
        // zero bins (aliases mje)
        {
            float* bf_ = &bins[0][0];
            for (int idx = tid; idx < 16*292; idx += 256) bf_[idx] = 0.f;
        }
        float mysum[4];
        #pragma unroll
        for (int reg = 0; reg < 4; ++reg) {
            int il = quad*4 + reg;
            float mx = fmaxf(fmaxf(red[0][0][il], red[0][1][il]), fmaxf(red[0][2][il], red[0][3][il]));
            float s = 0.f;
            #pragma unroll
            for (int ct = 0; ct < 8; ++ct) { float ex = __expf(sc[ct][reg] - mx); sc[ct][reg] = ex; s += ex; }
            #pragma unroll
            for (int o = 1; o < 16; o <<= 1) s += __shfl_xor(s, o, 16);
            mysum[reg] = s;
        }
        if (lr == 0) {
            #pragma unroll
            for (int reg = 0; reg < 4; ++reg) red[1][w][quad*4 + reg] = mysum[reg];
        }
        __syncthreads();   // B3: red[1] ready AND bins zeroed
        float inv_[4];
        #pragma unroll
        for (int reg = 0; reg < 4; ++reg) {
            int il = quad*4 + reg;
            inv_[reg] = 1.0f / (red[1][0][il] + red[1][1][il] + red[1][2][il] + red[1][3][il]);
        }
        // P write + bins scatter (pk from registers; mje is gone)
        #pragma unroll
        for (int ct = 0; ct < 8; ++ct) {
            int j = jbase + ct*16 + lr;
            #pragma unroll
            for (int reg = 0; reg < 4; ++reg) {
                int il = quad*4 + reg;
                float ps = sc[ct][reg] * inv_[reg];
                Pl[il][j] = (unsigned short)f2bs(ps);
                unsigned int pk = (pk2[ct][reg>>1] >> ((reg&1)*16)) & 0xFFFFu;
                atomicAdd(&bins[il][pk & 511], ps);
                atomicAdd(&bins[il][264 + (int)(pk >> 9)], ps);
            }
        }
    }
    __syncthreads();   // B4: Pl + bins complete

    // ---- dump bins -> qhe rows (vha, bf16) ----
    {
        int rowd = tid >> 4, c0 = tid & 15;
        unsigned short* dst = qhe + ((size_t)bh*NN + i0 + rowd)*QHE_S;
        for (int c = c0; c < 292; c += 16) dst[c] = (unsigned short)f2bs(bins[rowd][c]);
    }

    // ---- PV via MFMA: wave w handles K-chunk [jbase, jbase+128) ----
    f32x4 acc0 = (f32x4){0.f,0.f,0.f,0.f};
    f32x4 acc1 = (f32x4){0.f,0.f,0.f,0.f};
    #pragma unroll
    for (int t = 0; t < 4; ++t) {
        int kk = jbase + t*32 + quad*8;
        short8 pa = *(const short8*)&Pl[lr][kk];
        short8 b0 = *(const short8*)(vT_bf + ((size_t)bh*DH + lr)*NN + kk);
        short8 b1 = *(const short8*)(vT_bf + ((size_t)bh*DH + 16 + lr)*NN + kk);
        acc0 = __builtin_amdgcn_mfma_f32_16x16x32_bf16(pa, b0, acc0, 0, 0, 0);
        acc1 = __builtin_amdgcn_mfma_f32_16x16x32_bf16(pa, b1, acc1, 0, 0, 0);
    }
    __syncthreads();   // B5: bins dump consumed -> safe to overwrite as cpart
    #pragma unroll
    for (int reg = 0; reg < 4; ++reg) {
        int il = quad*4 + reg;
        cpart[((size_t)w*16 + il)*32 + lr]      = acc0[reg];
        cpart[((size_t)w*16 + il)*32 + 16 + lr] = acc1[reg];
    }
    __syncthreads();   // B6
    {
        int rowd = tid >> 4, dd = (tid & 15)*2;
        float v0 = 0.f, v1 = 0.f;
        #pragma unroll
        for (int ww = 0; ww < 4; ++ww) {
            v0 += cpart[((size_t)ww*16 + rowd)*32 + dd];
            v1 += cpart[((size_t)ww*16 + rowd)*32 + dd + 1];
        }
        float* cp = ctx + ((size_t)b*NN + i0 + rowd)*DM + hh*DH + dd;
        cp[0] = v0; cp[1] = v1;
    }
}

// ---------------- k_av2: ctx[b,i,h*32+d] += vha[bh,i,:] @ vhve_d[h][d][:]  via MFMA (K=320) ----------------
__global__ __launch_bounds__(256) void k_av2(const unsigned short* __restrict__ vha,
                                             const unsigned short* __restrict__ vhve_d,
                                             float* __restrict__ ctx) {
    int bh = blockIdx.x;
    int hh = bh & (NH-1);
    int b  = bh >> 3;
    int r0 = blockIdx.y * 64;
    int tid = threadIdx.x;
    int w = tid >> 6, l = tid & 63;
    int quad = l >> 4, lr = l & 15;

    const unsigned short* arow = vha + ((size_t)bh*NN + r0 + w*16 + lr)*QHE_S + quad*8;
    const unsigned short* br0  = vhve_d + ((size_t)hh*32 + lr)*320 + quad*8;
    const unsigned short* br1  = vhve_d + ((size_t)hh*32 + 16 + lr)*320 + quad*8;

    f32x4 acc0 = (f32x4){0.f,0.f,0.f,0.f};
    f32x4 acc1 = (f32x4){0.f,0.f,0.f,0.f};
    #pragma unroll
    for (int k0 = 0; k0 < 320; k0 += 32) {
        short8 af = *(const short8*)(arow + k0);
        short8 b0 = *(const short8*)(br0 + k0);
        short8 b1 = *(const short8*)(br1 + k0);
        acc0 = __builtin_amdgcn_mfma_f32_16x16x32_bf16(af, b0, acc0, 0, 0, 0);
        acc1 = __builtin_amdgcn_mfma_f32_16x16x32_bf16(af, b1, acc1, 0, 0, 0);
    }
    #pragma unroll
    for (int reg = 0; reg < 4; ++reg) {
        int row = r0 + w*16 + quad*4 + reg;
        float* cp = ctx + ((size_t)b*NN + row)*DM + hh*DH;
        cp[lr]      += acc0[reg];
        cp[16 + lr] += acc1[reg];
    }
}

extern "C" void kernel_launch(void* const* d_in, const int* in_sizes, int n_in,
                              void* d_out, int out_size, void* d_ws, size_t ws_size,
                              hipStream_t stream) {
    const float* x     = (const float*)d_in[0];
    const unsigned char* mask = (const unsigned char*)d_in[1];
    const int*   dist  = (const int*)d_in[2];
    const int*   edge  = (const int*)d_in[3];
    const float* node_W = (const float*)d_in[4];
    const float* node_b = (const float*)d_in[5];
    const float* ln1_g = (const float*)d_in[6];
    const float* ln1_b = (const float*)d_in[7];
    const float* Wq = (const float*)d_in[8];
    const float* bq = (const float*)d_in[9];
    const float* Wk = (const float*)d_in[10];
    const float* bk = (const float*)d_in[11];
    const float* Wv = (const float*)d_in[12];
    const float* bv = (const float*)d_in[13];
    const float* Wo = (const float*)d_in[14];
    const float* bo = (const float*)d_in[15];
    const float* ln2_g = (const float*)d_in[16];
    const float* ln2_b = (const float*)d_in[17];
    const float* W1 = (const float*)d_in[18];
    const float* b1 = (const float*)d_in[19];
    const float* W2 = (const float*)d_in[20];
    const float* b2 = (const float*)d_in[21];
    const float* q_hop  = (const float*)d_in[22];
    const float* q_edge = (const float*)d_in[23];
    const float* k_hop  = (const float*)d_in[24];
    const float* k_edge = (const float*)d_in[25];
    const float* v_hop  = (const float*)d_in[26];
    const float* v_edge = (const float*)d_in[27];
    const float* fln_g = (const float*)d_in[28];
    const float* fln_b = (const float*)d_in[29];
    const float* out_W = (const float*)d_in[30];
    const float* out_b = (const float*)d_in[31];
    float* out = (float*)d_out;

    float* ws = (float*)d_ws;
    float* h   = ws + 0;                          // 2,097,152
    float* y   = ws + 2097152;                    // 2,097,152
    unsigned short* q_bf  = (unsigned short*)(ws + 4194304);   // 2,097,152 ushorts
    unsigned short* k_bf  = (unsigned short*)(ws + 5242880);
    unsigned short* vT_bf = (unsigned short*)(ws + 6291456);   // [bh][d][n]
    float* ctx = ws + 7340032;                    // 2,097,152
    unsigned short* kht = (unsigned short*)(ws + 9437184);     // 128*258*512 ushorts (8,454,144 floats)
    float* ffn = ws + 9437184;                    // 8,388,608 floats (aliases kht, dead by then)
    unsigned short* qhe = (unsigned short*)(ws + 17891328);    // 128*512*296 ushorts; becomes vha
    // small tables alias y (y dead between qkv-GEMMs and ln2)
    unsigned short* w2     = (unsigned short*)(y);             // 8*304*64 ushorts
    unsigned short* vhve_d = (unsigned short*)(y + 81920);     // 8*32*320 ushorts

    k_mgemm<DIN, DM, 0, 0, 0><<<dim3(ROWS/64, DM/64), 256, 0, stream>>>(x, node_W, node_b, h);
    k_ln<<<ROWS/4, 256, 0, stream>>>(h, ln1_g, ln1_b, y);
    k_mgemm<DM, DM, 0, 0, 1><<<dim3(ROWS/64, DM/64), 256, 0, stream>>>(y, Wq, bq, q_bf);
    k_mgemm<DM, DM, 0, 0, 1><<<dim3(ROWS/64, DM/64), 256, 0, stream>>>(y, Wk, bk, k_bf);
    k_mgemm<DM, DM, 0, 0, 2><<<dim3(ROWS/64, DM/64), 256, 0, stream>>>(y, Wv, bv, vT_bf);
    // y now dead -> build fused tables
    k_prep<<<NH, 256, 0, stream>>>(q_hop, q_edge, k_edge, v_hop, v_edge, w2, vhve_d);
    k_kht2<<<dim3(BB*NH, 5), 256, 0, stream>>>(k_bf, k_hop, kht);
    k_qhe2<<<dim3(BB*NH, NN/64), 256, 0, stream>>>(q_bf, k_bf, w2, qhe);
    k_score<<<BB*NH*(NN/16), 256, 0, stream>>>(q_bf, k_bf, vT_bf, kht, dist, edge, mask, qhe, ctx);
    k_av2<<<dim3(BB*NH, NN/64), 256, 0, stream>>>(qhe, vhve_d, ctx);
    k_mgemm<DM, DM, 0, 1, 0><<<dim3(ROWS/64, DM/64), 256, 0, stream>>>(ctx, Wo, bo, h);
    k_ln<<<ROWS/4, 256, 0, stream>>>(h, ln2_g, ln2_b, y);
    k_mgemm<DM, FF, 1, 0, 0><<<dim3(ROWS/64, FF/64), 256, 0, stream>>>(y, W1, b1, ffn);
    k_mgemm<FF, DM, 0, 1, 0><<<dim3(ROWS/64, DM/64), 256, 0, stream>>>(ffn, W2, b2, h);
    k_ln<<<ROWS/4, 256, 0, stream>>>(h, fln_g, fln_b, y);
    k_mgemm<DM, DOUT, 0, 0, 0><<<dim3(ROWS/64, DOUT/64), 256, 0, stream>>>(y, out_W, out_b, out);
}

// Round 3
// 728.060 us; speedup vs baseline: 1.1445x; 1.1445x over previous
//
#include <hip/hip_runtime.h>
#include <hip/hip_bf16.h>
#include <math.h>

#define BB 16
#define NN 512
#define DIN 128
#define DM 256
#define NH 8
#define DH 32
#define FF 1024
#define DOUT 128
#define NHOP 258
#define NEDGE 27
#define ROWS (BB*NN)   // 8192
#define QHE_S 296      // qhe row stride (ushorts): qh 0..257, qec at 264..290; becomes vha bins after k_score

typedef short short8 __attribute__((ext_vector_type(8)));
typedef float f32x4 __attribute__((ext_vector_type(4)));

static __device__ __forceinline__ float bf2f(unsigned short u) {
    union { float f; unsigned int i; } c; c.i = ((unsigned int)u) << 16; return c.f;
}
static __device__ __forceinline__ short f2bs(float f) {
    __hip_bfloat16 h = __float2bfloat16(f);
    return *reinterpret_cast<short*>(&h);
}

// ---------------- layernorm: one wave per row, float4 + shuffle ----------------
__global__ __launch_bounds__(256) void k_ln(const float* __restrict__ in, const float* __restrict__ g,
                                            const float* __restrict__ bta, float* __restrict__ out) {
    int row = blockIdx.x * 4 + (threadIdx.x >> 6);
    int l = threadIdx.x & 63;
    float4 xv = ((const float4*)(in + (size_t)row*DM))[l];
    float s = xv.x + xv.y + xv.z + xv.w;
    #pragma unroll
    for (int o = 32; o > 0; o >>= 1) s += __shfl_xor(s, o, 64);
    float mean = s * (1.0f/DM);
    float dx = xv.x-mean, dy = xv.y-mean, dz = xv.z-mean, dw = xv.w-mean;
    float vs = dx*dx + dy*dy + dz*dz + dw*dw;
    #pragma unroll
    for (int o = 32; o > 0; o >>= 1) vs += __shfl_xor(vs, o, 64);
    float r = rsqrtf(vs * (1.0f/DM) + 1e-5f);
    float4 gg = ((const float4*)g)[l];
    float4 bb = ((const float4*)bta)[l];
    float4 ov; ov.x = dx*r*gg.x+bb.x; ov.y = dy*r*gg.y+bb.y; ov.z = dz*r*gg.z+bb.z; ov.w = dw*r*gg.w+bb.w;
    ((float4*)(out + (size_t)row*DM))[l] = ov;
}

// ---------------- MFMA bf16 GEMM: 64x64 tile, fp32 in, bf16 staging ----------------
// QKV=0: fp32 out (ACT=gelu, RES=+=). QKV=1: bf16 out [B,H,N,DH]. QKV=2: bf16 out transposed [B,H,DH,N].
template<int K, int N, int ACT, int RES, int QKV>
__global__ __launch_bounds__(256) void k_mgemm(const float* __restrict__ A, const float* __restrict__ W,
                                               const float* __restrict__ bias, void* __restrict__ outv) {
    __shared__ __align__(16) short As[64][40];   // [m][k] bf16
    __shared__ __align__(16) short Bs[64][40];   // [n][k] bf16
    int r0 = blockIdx.x * 64;
    int n0 = blockIdx.y * 64;
    int tid = threadIdx.x;
    int w = tid >> 6, l = tid & 63;

    f32x4 acc[4];
    #pragma unroll
    for (int c = 0; c < 4; ++c) acc[c] = (f32x4){0.f,0.f,0.f,0.f};

    for (int k0 = 0; k0 < K; k0 += 32) {
        __syncthreads();
        {
            int m = tid >> 2, ks = (tid & 3) * 8;
            const float* src = A + (size_t)(r0 + m)*K + k0 + ks;
            float4 f0 = *(const float4*)src;
            float4 f1 = *(const float4*)(src + 4);
            short8 pk;
            pk[0]=f2bs(f0.x); pk[1]=f2bs(f0.y); pk[2]=f2bs(f0.z); pk[3]=f2bs(f0.w);
            pk[4]=f2bs(f1.x); pk[5]=f2bs(f1.y); pk[6]=f2bs(f1.z); pk[7]=f2bs(f1.w);
            *(short8*)&As[m][ks] = pk;
        }
        {
            int n = tid & 63, kg = tid >> 6;
            const float* wp = W + (size_t)(k0 + kg*8)*N + n0 + n;
            short8 pk;
            #pragma unroll
            for (int j = 0; j < 8; ++j) pk[j] = f2bs(wp[(size_t)j*N]);
            *(short8*)&Bs[n][kg*8] = pk;
        }
        __syncthreads();
        short8 af = *(short8*)&As[w*16 + (l & 15)][(l >> 4)*8];
        #pragma unroll
        for (int c = 0; c < 4; ++c) {
            short8 bf = *(short8*)&Bs[c*16 + (l & 15)][(l >> 4)*8];
            acc[c] = __builtin_amdgcn_mfma_f32_16x16x32_bf16(af, bf, acc[c], 0, 0, 0);
        }
    }

    int quad = l >> 4;
    #pragma unroll
    for (int c = 0; c < 4; ++c) {
        int col = n0 + c*16 + (l & 15);
        float bv = bias[col];
        #pragma unroll
        for (int reg = 0; reg < 4; ++reg) {
            int row = r0 + w*16 + quad*4 + reg;
            float val = acc[c][reg] + bv;
            if (ACT) val = 0.5f * val * (1.0f + erff(val * 0.70710678118654752f));
            if (QKV == 1) {
                unsigned short* out = (unsigned short*)outv;
                int b = row >> 9, n = row & (NN-1);
                int hh = col >> 5, d = col & (DH-1);
                out[(size_t)((b*NH + hh)*NN + n)*DH + d] = (unsigned short)f2bs(val);
            } else if (QKV == 2) {
                unsigned short* out = (unsigned short*)outv;
                int b = row >> 9, n = row & (NN-1);
                int hh = col >> 5, d = col & (DH-1);
                out[(size_t)((b*NH + hh)*DH + d)*NN + n] = (unsigned short)f2bs(val);
            } else if (RES) {
                ((float*)outv)[(size_t)row*N + col] += val;
            } else {
                ((float*)outv)[(size_t)row*N + col] = val;
            }
        }
    }
}

// ---------------- k_prep: build w2[8][304][64] bf16 and vhve_d[8][32][320] bf16 ----------------
__global__ __launch_bounds__(256) void k_prep(const float* __restrict__ q_hop, const float* __restrict__ q_edge,
                                              const float* __restrict__ k_edge, const float* __restrict__ v_hop,
                                              const float* __restrict__ v_edge,
                                              unsigned short* __restrict__ w2, unsigned short* __restrict__ vhve_d) {
    int h = blockIdx.x;
    int tid = threadIdx.x;
    for (int idx = tid; idx < 304*64; idx += 256) {
        int n = idx >> 6, kk = idx & 63;
        float val = 0.f;
        if (n < NHOP && kk < 32) val = q_hop[(size_t)n*DM + h*DH + kk];
        else if (n >= 264 && n < 264 + NEDGE) {
            int e = n - 264;
            val = (kk < 32) ? q_edge[(size_t)e*DM + h*DH + kk]
                            : k_edge[(size_t)e*DM + h*DH + (kk - 32)];
        }
        w2[((size_t)h*304 + n)*64 + kk] = (unsigned short)f2bs(val);
    }
    for (int idx = tid; idx < 32*320; idx += 256) {
        int d = idx / 320, kk = idx - d*320;
        float val = 0.f;
        if (kk < NHOP) val = v_hop[(size_t)kk*DM + h*DH + d];
        else if (kk >= 264 && kk < 264 + NEDGE) val = v_edge[(size_t)(kk-264)*DM + h*DH + d];
        vhve_d[((size_t)h*32 + d)*320 + kk] = (unsigned short)f2bs(val);
    }
}

// ---------------- k_kht2: kht[bh][m][j] = Kh[h][m][:] @ k_bf[bh][j][:]  via MFMA ----------------
__global__ __launch_bounds__(256) void k_kht2(const unsigned short* __restrict__ k_bf,
                                              const float* __restrict__ k_hop,
                                              unsigned short* __restrict__ kht) {
    int bh = blockIdx.x;
    int hh = bh & (NH-1);
    int r0 = blockIdx.y * 64;   // m tile
    int tid = threadIdx.x;
    int w = tid >> 6, l = tid & 63;
    int quad = l >> 4, lr = l & 15;

    int m = r0 + w*16 + lr;
    int mc = m < NHOP ? m : NHOP-1;
    const float* ar = k_hop + (size_t)mc*DM + hh*DH + quad*8;
    float4 a0 = *(const float4*)ar;
    float4 a1 = *(const float4*)(ar + 4);
    short8 af;
    af[0]=f2bs(a0.x); af[1]=f2bs(a0.y); af[2]=f2bs(a0.z); af[3]=f2bs(a0.w);
    af[4]=f2bs(a1.x); af[5]=f2bs(a1.y); af[6]=f2bs(a1.z); af[7]=f2bs(a1.w);

    for (int ct = 0; ct < 32; ++ct) {
        short8 bf = *(const short8*)(k_bf + ((size_t)bh*NN + ct*16 + lr)*DH + quad*8);
        f32x4 acc = (f32x4){0.f,0.f,0.f,0.f};
        acc = __builtin_amdgcn_mfma_f32_16x16x32_bf16(af, bf, acc, 0, 0, 0);
        #pragma unroll
        for (int reg = 0; reg < 4; ++reg) {
            int m2 = r0 + w*16 + quad*4 + reg;
            if (m2 < NHOP)
                kht[((size_t)bh*NHOP + m2)*NN + ct*16 + lr] = (unsigned short)f2bs(acc[reg]);
        }
    }
}

// ---------------- k_qhe2: qhe rows via MFMA; A = [q_bf | k_bf] (K=64), B^T = w2 ----------------
__global__ __launch_bounds__(256) void k_qhe2(const unsigned short* __restrict__ q_bf,
                                              const unsigned short* __restrict__ k_bf,
                                              const unsigned short* __restrict__ w2,
                                              unsigned short* __restrict__ qhe) {
    int bh = blockIdx.x;
    int hh = bh & (NH-1);
    int r0 = blockIdx.y * 64;
    int tid = threadIdx.x;
    int w = tid >> 6, l = tid & 63;
    int quad = l >> 4, lr = l & 15;

    int row0 = r0 + w*16 + lr;
    short8 af0 = *(const short8*)(q_bf + ((size_t)bh*NN + row0)*DH + quad*8);
    short8 af1 = *(const short8*)(k_bf + ((size_t)bh*NN + row0)*DH + quad*8);

    const unsigned short* w2h = w2 + (size_t)hh*304*64;
    for (int ct = 0; ct < 19; ++ct) {
        int col = ct*16 + lr;
        short8 b0 = *(const short8*)(w2h + (size_t)col*64 + quad*8);
        short8 b1 = *(const short8*)(w2h + (size_t)col*64 + 32 + quad*8);
        f32x4 acc = (f32x4){0.f,0.f,0.f,0.f};
        acc = __builtin_amdgcn_mfma_f32_16x16x32_bf16(af0, b0, acc, 0, 0, 0);
        acc = __builtin_amdgcn_mfma_f32_16x16x32_bf16(af1, b1, acc, 0, 0, 0);
        if (col < QHE_S) {
            #pragma unroll
            for (int reg = 0; reg < 4; ++reg) {
                int row = r0 + w*16 + quad*4 + reg;
                qhe[((size_t)bh*NN + row)*QHE_S + col] = (unsigned short)f2bs(acc[reg]);
            }
        }
    }
}

// ---------------- k_score: flash-style MFMA. block = (b, head, 16-row i-tile); 4 waves ----------------
// v4: r0's exact instruction stream (pk re-read from mje, no register stash -> no spill),
//     LDS shrunk 52K -> 35.6K by SEQUENTIAL aliasing: bins overlays Pl's region, valid because
//     PV's Pl reads are intra-wave (each wave reads only the j-chunk it wrote) and run BEFORE
//     the bins zero+scatter. mje keeps its own region (pk codes live until scatter, like r0).
//     4 blocks/CU (was 3). Plain __launch_bounds__(256): r0's allocator gave 68 VGPR, no spill.
__global__ __launch_bounds__(256) void k_score(
    const unsigned short* __restrict__ q_bf, const unsigned short* __restrict__ k_bf,
    const unsigned short* __restrict__ vT_bf, const unsigned short* __restrict__ kht,
    const int* __restrict__ dist, const int* __restrict__ edge,
    const unsigned char* __restrict__ mask, unsigned short* __restrict__ qhe,
    float* __restrict__ ctx)
{
    int g = blockIdx.x;                 // 4096
    int r = g >> 3;                     // 0..511
    int b = (g & 7) + ((r >> 8) << 3);  // XCD-affine
    int rem = r & 255;
    int hh = rem >> 5;
    int i0 = (rem & 31) << 4;
    int bh = b*NH + hh;
    int tid = threadIdx.x;
    int w = tid >> 6, l = tid & 63;
    int lr = l & 15, quad = l >> 4;

    // LDS layout (35584 B):
    //   [0, 16384)      mje[16][512] u16      (phase A -> last read in scatter)
    //   [16384, 33024)  Pl[16][520] u16       (P-write -> PV, intra-wave)
    //   [16384, 35072)  bins[16][292] f32     (aliases Pl; zero -> scatter -> dump, after PV)
    //   [0, 8192)       cpart[4][16][32] f32  (aliases mje; after scatter)
    //   [35072, 35584)  red[2][4][16] f32
    __shared__ __align__(16) unsigned char smem[35584];
    unsigned short (*mje)[512] = (unsigned short(*)[512])smem;
    unsigned short (*Pl)[520] = (unsigned short(*)[520])(smem + 16384);
    float (*bins)[292] = (float(*)[292])(smem + 16384);
    float (*red)[4][16] = (float(*)[4][16])(smem + 35072);
    float* cpart = (float*)smem;

    // ---- phase A: decode dist/edge (16 contiguous rows) -> mje, coalesced int4 ----
    {
        const int4* dp = (const int4*)(dist + ((size_t)b*NN + i0)*NN);
        const int4* ep = (const int4*)(edge + ((size_t)b*NN + i0)*NN);
        unsigned short* mf = &mje[0][0];
        for (int idx = tid; idx < 2048; idx += 256) {
            int4 dv = dp[idx];
            int4 ev = ep[idx];
            int m0 = dv.x > 256 ? 256 : dv.x; if (dv.x < 0) m0 = 257;
            int m1 = dv.y > 256 ? 256 : dv.y; if (dv.y < 0) m1 = 257;
            int m2 = dv.z > 256 ? 256 : dv.z; if (dv.z < 0) m2 = 257;
            int m3 = dv.w > 256 ? 256 : dv.w; if (dv.w < 0) m3 = 257;
            int e0 = ev.x > 25 ? 25 : ev.x; if (ev.x < 0) e0 = 26;
            int e1 = ev.y > 25 ? 25 : ev.y; if (ev.y < 0) e1 = 26;
            int e2 = ev.z > 25 ? 25 : ev.z; if (ev.z < 0) e2 = 26;
            int e3 = ev.w > 25 ? 25 : ev.w; if (ev.w < 0) e3 = 26;
            uint2 pk;
            pk.x = (unsigned)(m0 | (e0<<9)) | ((unsigned)(m1 | (e1<<9)) << 16);
            pk.y = (unsigned)(m2 | (e2<<9)) | ((unsigned)(m3 | (e3<<9)) << 16);
            *(uint2*)&mf[idx*4] = pk;
        }
    }
    __syncthreads();   // B1: mje ready

    // ---- phase B: QK^T via MFMA (wave w covers j in [w*128, w*128+128)) ----
    int jbase = w*128;
    short8 af = *(const short8*)(q_bf + ((size_t)bh*NN + i0 + lr)*DH + quad*8);
    f32x4 sc[8];
    #pragma unroll
    for (int ct = 0; ct < 8; ++ct) {
        short8 bfr = *(const short8*)(k_bf + ((size_t)bh*NN + jbase + ct*16 + lr)*DH + quad*8);
        f32x4 z = (f32x4){0.f,0.f,0.f,0.f};
        sc[ct] = __builtin_amdgcn_mfma_f32_16x16x32_bf16(af, bfr, z, 0, 0, 0);
    }

    // ---- phase C: bias gathers + mask (pk read from mje LDS, exactly as r0) ----
    const unsigned short* khtb = kht + (size_t)bh*NHOP*NN;
    const unsigned char* mrow = mask + (size_t)b*NN;
    const float scale = 0.17677669529663687f;
    unsigned char msk[8];
    #pragma unroll
    for (int ct = 0; ct < 8; ++ct) msk[ct] = mrow[jbase + ct*16 + lr];

    #pragma unroll
    for (int ct = 0; ct < 8; ++ct) {
        int j = jbase + ct*16 + lr;
        #pragma unroll
        for (int reg = 0; reg < 4; ++reg) {
            int il = quad*4 + reg;
            int pk = mje[il][j];
            int m = pk & 511, e = pk >> 9;
            const unsigned short* qhr = qhe + ((size_t)bh*NN + i0 + il)*QHE_S;
            float a = sc[ct][reg] + bf2f(khtb[(size_t)m*NN + j]) + bf2f(qhr[m]) + bf2f(qhr[264 + e]);
            a *= scale;
            if (msk[ct]) a = -INFINITY;
            sc[ct][reg] = a;
        }
    }

    // ---- softmax across all 512 j (cross-wave via LDS) ----
    {
        float mymax[4];
        #pragma unroll
        for (int reg = 0; reg < 4; ++reg) {
            float mx = sc[0][reg];
            #pragma unroll
            for (int ct = 1; ct < 8; ++ct) mx = fmaxf(mx, sc[ct][reg]);
            #pragma unroll
            for (int o = 1; o < 16; o <<= 1) mx = fmaxf(mx, __shfl_xor(mx, o, 16));
            mymax[reg] = mx;
        }
        if (lr == 0) {
            #pragma unroll
            for (int reg = 0; reg < 4; ++reg) red[0][w][quad*4 + reg] = mymax[reg];
        }
        __syncthreads();   // B2: red[0] ready
        float mysum[4];
        #pragma unroll
        for (int reg = 0; reg < 4; ++reg) {
            int il = quad*4 + reg;
            float mx = fmaxf(fmaxf(red[0][0][il], red[0][1][il]), fmaxf(red[0][2][il], red[0][3][il]));
            float s = 0.f;
            #pragma unroll
            for (int ct = 0; ct < 8; ++ct) { float ex = __expf(sc[ct][reg] - mx); sc[ct][reg] = ex; s += ex; }
            #pragma unroll
            for (int o = 1; o < 16; o <<= 1) s += __shfl_xor(s, o, 16);
            mysum[reg] = s;
        }
        if (lr == 0) {
            #pragma unroll
            for (int reg = 0; reg < 4; ++reg) red[1][w][quad*4 + reg] = mysum[reg];
        }
        __syncthreads();   // B3: red[1] ready
        float inv_[4];
        #pragma unroll
        for (int reg = 0; reg < 4; ++reg) {
            int il = quad*4 + reg;
            inv_[reg] = 1.0f / (red[1][0][il] + red[1][1][il] + red[1][2][il] + red[1][3][il]);
        }
        // ---- P write only (normalize sc in place; bins scatter deferred until after PV) ----
        #pragma unroll
        for (int ct = 0; ct < 8; ++ct) {
            int j = jbase + ct*16 + lr;
            #pragma unroll
            for (int reg = 0; reg < 4; ++reg) {
                int il = quad*4 + reg;
                float ps = sc[ct][reg] * inv_[reg];
                sc[ct][reg] = ps;
                Pl[il][j] = (unsigned short)f2bs(ps);
            }
        }
    }

    // ---- PV via MFMA: wave w handles K-chunk [jbase, jbase+128) ----
    // Pl reads are intra-wave (this wave wrote exactly these rows/cols) -> no barrier needed.
    f32x4 acc0 = (f32x4){0.f,0.f,0.f,0.f};
    f32x4 acc1 = (f32x4){0.f,0.f,0.f,0.f};
    #pragma unroll
    for (int t = 0; t < 4; ++t) {
        int kk = jbase + t*32 + quad*8;
        short8 pa = *(const short8*)&Pl[lr][kk];
        short8 b0 = *(const short8*)(vT_bf + ((size_t)bh*DH + lr)*NN + kk);
        short8 b1 = *(const short8*)(vT_bf + ((size_t)bh*DH + 16 + lr)*NN + kk);
        acc0 = __builtin_amdgcn_mfma_f32_16x16x32_bf16(pa, b0, acc0, 0, 0, 0);
        acc1 = __builtin_amdgcn_mfma_f32_16x16x32_bf16(pa, b1, acc1, 0, 0, 0);
    }
    __syncthreads();   // B4: all waves done reading Pl -> bins may overwrite its region

    // ---- zero bins (aliases Pl) ----
    {
        float* bf_ = &bins[0][0];
        for (int idx = tid; idx < 16*292; idx += 256) bf_[idx] = 0.f;
    }
    __syncthreads();   // B5: bins zeroed

    // ---- bins scatter: pk re-read from mje (r0 pattern, no register stash); ps from sc ----
    #pragma unroll
    for (int ct = 0; ct < 8; ++ct) {
        int j = jbase + ct*16 + lr;
        #pragma unroll
        for (int reg = 0; reg < 4; ++reg) {
            int il = quad*4 + reg;
            int pk = mje[il][j];
            float ps = sc[ct][reg];
            atomicAdd(&bins[il][pk & 511], ps);
            atomicAdd(&bins[il][264 + (pk >> 9)], ps);
        }
    }
    __syncthreads();   // B6: bins complete; mje dead -> cpart alias safe

    // ---- dump bins -> qhe rows (vha, bf16) ----
    {
        int rowd = tid >> 4, c0 = tid & 15;
        unsigned short* dst = qhe + ((size_t)bh*NN + i0 + rowd)*QHE_S;
        for (int c = c0; c < 292; c += 16) dst[c] = (unsigned short)f2bs(bins[rowd][c]);
    }

    // ---- ctx partial reduce across waves (cpart aliases mje) ----
    #pragma unroll
    for (int reg = 0; reg < 4; ++reg) {
        int il = quad*4 + reg;
        cpart[((size_t)w*16 + il)*32 + lr]      = acc0[reg];
        cpart[((size_t)w*16 + il)*32 + 16 + lr] = acc1[reg];
    }
    __syncthreads();   // B7: cpart ready
    {
        int rowd = tid >> 4, dd = (tid & 15)*2;
        float v0 = 0.f, v1 = 0.f;
        #pragma unroll
        for (int ww = 0; ww < 4; ++ww) {
            v0 += cpart[((size_t)ww*16 + rowd)*32 + dd];
            v1 += cpart[((size_t)ww*16 + rowd)*32 + dd + 1];
        }
        float* cp = ctx + ((size_t)b*NN + i0 + rowd)*DM + hh*DH + dd;
        cp[0] = v0; cp[1] = v1;
    }
}

// ---------------- k_av2: ctx[b,i,h*32+d] += vha[bh,i,:] @ vhve_d[h][d][:]  via MFMA (K=320) ----------------
__global__ __launch_bounds__(256) void k_av2(const unsigned short* __restrict__ vha,
                                             const unsigned short* __restrict__ vhve_d,
                                             float* __restrict__ ctx) {
    int bh = blockIdx.x;
    int hh = bh & (NH-1);
    int b  = bh >> 3;
    int r0 = blockIdx.y * 64;
    int tid = threadIdx.x;
    int w = tid >> 6, l = tid & 63;
    int quad = l >> 4, lr = l & 15;

    const unsigned short* arow = vha + ((size_t)bh*NN + r0 + w*16 + lr)*QHE_S + quad*8;
    const unsigned short* br0  = vhve_d + ((size_t)hh*32 + lr)*320 + quad*8;
    const unsigned short* br1  = vhve_d + ((size_t)hh*32 + 16 + lr)*320 + quad*8;

    f32x4 acc0 = (f32x4){0.f,0.f,0.f,0.f};
    f32x4 acc1 = (f32x4){0.f,0.f,0.f,0.f};
    #pragma unroll
    for (int k0 = 0; k0 < 320; k0 += 32) {
        short8 af = *(const short8*)(arow + k0);
        short8 b0 = *(const short8*)(br0 + k0);
        short8 b1 = *(const short8*)(br1 + k0);
        acc0 = __builtin_amdgcn_mfma_f32_16x16x32_bf16(af, b0, acc0, 0, 0, 0);
        acc1 = __builtin_amdgcn_mfma_f32_16x16x32_bf16(af, b1, acc1, 0, 0, 0);
    }
    #pragma unroll
    for (int reg = 0; reg < 4; ++reg) {
        int row = r0 + w*16 + quad*4 + reg;
        float* cp = ctx + ((size_t)b*NN + row)*DM + hh*DH;
        cp[lr]      += acc0[reg];
        cp[16 + lr] += acc1[reg];
    }
}

extern "C" void kernel_launch(void* const* d_in, const int* in_sizes, int n_in,
                              void* d_out, int out_size, void* d_ws, size_t ws_size,
                              hipStream_t stream) {
    const float* x     = (const float*)d_in[0];
    const unsigned char* mask = (const unsigned char*)d_in[1];
    const int*   dist  = (const int*)d_in[2];
    const int*   edge  = (const int*)d_in[3];
    const float* node_W = (const float*)d_in[4];
    const float* node_b = (const float*)d_in[5];
    const float* ln1_g = (const float*)d_in[6];
    const float* ln1_b = (const float*)d_in[7];
    const float* Wq = (const float*)d_in[8];
    const float* bq = (const float*)d_in[9];
    const float* Wk = (const float*)d_in[10];
    const float* bk = (const float*)d_in[11];
    const float* Wv = (const float*)d_in[12];
    const float* bv = (const float*)d_in[13];
    const float* Wo = (const float*)d_in[14];
    const float* bo = (const float*)d_in[15];
    const float* ln2_g = (const float*)d_in[16];
    const float* ln2_b = (const float*)d_in[17];
    const float* W1 = (const float*)d_in[18];
    const float* b1 = (const float*)d_in[19];
    const float* W2 = (const float*)d_in[20];
    const float* b2 = (const float*)d_in[21];
    const float* q_hop  = (const float*)d_in[22];
    const float* q_edge = (const float*)d_in[23];
    const float* k_hop  = (const float*)d_in[24];
    const float* k_edge = (const float*)d_in[25];
    const float* v_hop  = (const float*)d_in[26];
    const float* v_edge = (const float*)d_in[27];
    const float* fln_g = (const float*)d_in[28];
    const float* fln_b = (const float*)d_in[29];
    const float* out_W = (const float*)d_in[30];
    const float* out_b = (const float*)d_in[31];
    float* out = (float*)d_out;

    float* ws = (float*)d_ws;
    float* h   = ws + 0;                          // 2,097,152
    float* y   = ws + 2097152;                    // 2,097,152
    unsigned short* q_bf  = (unsigned short*)(ws + 4194304);   // 2,097,152 ushorts
    unsigned short* k_bf  = (unsigned short*)(ws + 5242880);
    unsigned short* vT_bf = (unsigned short*)(ws + 6291456);   // [bh][d][n]
    float* ctx = ws + 7340032;                    // 2,097,152
    unsigned short* kht = (unsigned short*)(ws + 9437184);     // 128*258*512 ushorts (8,454,144 floats)
    float* ffn = ws + 9437184;                    // 8,388,608 floats (aliases kht, dead by then)
    unsigned short* qhe = (unsigned short*)(ws + 17891328);    // 128*512*296 ushorts; becomes vha
    // small tables alias y (y dead between qkv-GEMMs and ln2)
    unsigned short* w2     = (unsigned short*)(y);             // 8*304*64 ushorts
    unsigned short* vhve_d = (unsigned short*)(y + 81920);     // 8*32*320 ushorts

    k_mgemm<DIN, DM, 0, 0, 0><<<dim3(ROWS/64, DM/64), 256, 0, stream>>>(x, node_W, node_b, h);
    k_ln<<<ROWS/4, 256, 0, stream>>>(h, ln1_g, ln1_b, y);
    k_mgemm<DM, DM, 0, 0, 1><<<dim3(ROWS/64, DM/64), 256, 0, stream>>>(y, Wq, bq, q_bf);
    k_mgemm<DM, DM, 0, 0, 1><<<dim3(ROWS/64, DM/64), 256, 0, stream>>>(y, Wk, bk, k_bf);
    k_mgemm<DM, DM, 0, 0, 2><<<dim3(ROWS/64, DM/64), 256, 0, stream>>>(y, Wv, bv, vT_bf);
    // y now dead -> build fused tables
    k_prep<<<NH, 256, 0, stream>>>(q_hop, q_edge, k_edge, v_hop, v_edge, w2, vhve_d);
    k_kht2<<<dim3(BB*NH, 5), 256, 0, stream>>>(k_bf, k_hop, kht);
    k_qhe2<<<dim3(BB*NH, NN/64), 256, 0, stream>>>(q_bf, k_bf, w2, qhe);
    k_score<<<BB*NH*(NN/16), 256, 0, stream>>>(q_bf, k_bf, vT_bf, kht, dist, edge, mask, qhe, ctx);
    k_av2<<<dim3(BB*NH, NN/64), 256, 0, stream>>>(qhe, vhve_d, ctx);
    k_mgemm<DM, DM, 0, 1, 0><<<dim3(ROWS/64, DM/64), 256, 0, stream>>>(ctx, Wo, bo, h);
    k_ln<<<ROWS/4, 256, 0, stream>>>(h, ln2_g, ln2_b, y);
    k_mgemm<DM, FF, 1, 0, 0><<<dim3(ROWS/64, FF/64), 256, 0, stream>>>(y, W1, b1, ffn);
    k_mgemm<FF, DM, 0, 1, 0><<<dim3(ROWS/64, DM/64), 256, 0, stream>>>(ffn, W2, b2, h);
    k_ln<<<ROWS/4, 256, 0, stream>>>(h, fln_g, fln_b, y);
    k_mgemm<DM, DOUT, 0, 0, 0><<<dim3(ROWS/64, DOUT/64), 256, 0, stream>>>(y, out_W, out_b, out);
}

// Round 4
// 727.101 us; speedup vs baseline: 1.1460x; 1.0013x over previous
//
#include <hip/hip_runtime.h>
#include <hip/hip_bf16.h>
#include <math.h>

#define BB 16
#define NN 512
#define DIN 128
#define DM 256
#define NH 8
#define DH 32
#define FF 1024
#define DOUT 128
#define NHOP 258
#define NEDGE 27
#define ROWS (BB*NN)   // 8192
#define QHE_S 296      // qhe row stride (ushorts): qh 0..257, qec at 264..290; becomes vha bins after k_score

typedef short short8 __attribute__((ext_vector_type(8)));
typedef float f32x4 __attribute__((ext_vector_type(4)));

static __device__ __forceinline__ float bf2f(unsigned short u) {
    union { float f; unsigned int i; } c; c.i = ((unsigned int)u) << 16; return c.f;
}
static __device__ __forceinline__ short f2bs(float f) {
    __hip_bfloat16 h = __float2bfloat16(f);
    return *reinterpret_cast<short*>(&h);
}

// ---------------- layernorm: one wave per row, float4 + shuffle ----------------
__global__ __launch_bounds__(256) void k_ln(const float* __restrict__ in, const float* __restrict__ g,
                                            const float* __restrict__ bta, float* __restrict__ out) {
    int row = blockIdx.x * 4 + (threadIdx.x >> 6);
    int l = threadIdx.x & 63;
    float4 xv = ((const float4*)(in + (size_t)row*DM))[l];
    float s = xv.x + xv.y + xv.z + xv.w;
    #pragma unroll
    for (int o = 32; o > 0; o >>= 1) s += __shfl_xor(s, o, 64);
    float mean = s * (1.0f/DM);
    float dx = xv.x-mean, dy = xv.y-mean, dz = xv.z-mean, dw = xv.w-mean;
    float vs = dx*dx + dy*dy + dz*dz + dw*dw;
    #pragma unroll
    for (int o = 32; o > 0; o >>= 1) vs += __shfl_xor(vs, o, 64);
    float r = rsqrtf(vs * (1.0f/DM) + 1e-5f);
    float4 gg = ((const float4*)g)[l];
    float4 bb = ((const float4*)bta)[l];
    float4 ov; ov.x = dx*r*gg.x+bb.x; ov.y = dy*r*gg.y+bb.y; ov.z = dz*r*gg.z+bb.z; ov.w = dw*r*gg.w+bb.w;
    ((float4*)(out + (size_t)row*DM))[l] = ov;
}

// ---------------- MFMA bf16 GEMM: 64x64 tile, fp32 in, bf16 staging ----------------
// QKV=0: fp32 out (ACT=gelu, RES=+=). QKV=1: bf16 out [B,H,N,DH]. QKV=2: bf16 out transposed [B,H,DH,N].
template<int K, int N, int ACT, int RES, int QKV>
__global__ __launch_bounds__(256) void k_mgemm(const float* __restrict__ A, const float* __restrict__ W,
                                               const float* __restrict__ bias, void* __restrict__ outv) {
    __shared__ __align__(16) short As[64][40];   // [m][k] bf16
    __shared__ __align__(16) short Bs[64][40];   // [n][k] bf16
    int r0 = blockIdx.x * 64;
    int n0 = blockIdx.y * 64;
    int tid = threadIdx.x;
    int w = tid >> 6, l = tid & 63;

    f32x4 acc[4];
    #pragma unroll
    for (int c = 0; c < 4; ++c) acc[c] = (f32x4){0.f,0.f,0.f,0.f};

    for (int k0 = 0; k0 < K; k0 += 32) {
        __syncthreads();
        {
            int m = tid >> 2, ks = (tid & 3) * 8;
            const float* src = A + (size_t)(r0 + m)*K + k0 + ks;
            float4 f0 = *(const float4*)src;
            float4 f1 = *(const float4*)(src + 4);
            short8 pk;
            pk[0]=f2bs(f0.x); pk[1]=f2bs(f0.y); pk[2]=f2bs(f0.z); pk[3]=f2bs(f0.w);
            pk[4]=f2bs(f1.x); pk[5]=f2bs(f1.y); pk[6]=f2bs(f1.z); pk[7]=f2bs(f1.w);
            *(short8*)&As[m][ks] = pk;
        }
        {
            int n = tid & 63, kg = tid >> 6;
            const float* wp = W + (size_t)(k0 + kg*8)*N + n0 + n;
            short8 pk;
            #pragma unroll
            for (int j = 0; j < 8; ++j) pk[j] = f2bs(wp[(size_t)j*N]);
            *(short8*)&Bs[n][kg*8] = pk;
        }
        __syncthreads();
        short8 af = *(short8*)&As[w*16 + (l & 15)][(l >> 4)*8];
        #pragma unroll
        for (int c = 0; c < 4; ++c) {
            short8 bf = *(short8*)&Bs[c*16 + (l & 15)][(l >> 4)*8];
            acc[c] = __builtin_amdgcn_mfma_f32_16x16x32_bf16(af, bf, acc[c], 0, 0, 0);
        }
    }

    int quad = l >> 4;
    #pragma unroll
    for (int c = 0; c < 4; ++c) {
        int col = n0 + c*16 + (l & 15);
        float bv = bias[col];
        #pragma unroll
        for (int reg = 0; reg < 4; ++reg) {
            int row = r0 + w*16 + quad*4 + reg;
            float val = acc[c][reg] + bv;
            if (ACT) val = 0.5f * val * (1.0f + erff(val * 0.70710678118654752f));
            if (QKV == 1) {
                unsigned short* out = (unsigned short*)outv;
                int b = row >> 9, n = row & (NN-1);
                int hh = col >> 5, d = col & (DH-1);
                out[(size_t)((b*NH + hh)*NN + n)*DH + d] = (unsigned short)f2bs(val);
            } else if (QKV == 2) {
                unsigned short* out = (unsigned short*)outv;
                int b = row >> 9, n = row & (NN-1);
                int hh = col >> 5, d = col & (DH-1);
                out[(size_t)((b*NH + hh)*DH + d)*NN + n] = (unsigned short)f2bs(val);
            } else if (RES) {
                ((float*)outv)[(size_t)row*N + col] += val;
            } else {
                ((float*)outv)[(size_t)row*N + col] = val;
            }
        }
    }
}

// ---------------- k_prep: build w2[8][304][64] bf16 and vhve_d[8][32][320] bf16 ----------------
__global__ __launch_bounds__(256) void k_prep(const float* __restrict__ q_hop, const float* __restrict__ q_edge,
                                              const float* __restrict__ k_edge, const float* __restrict__ v_hop,
                                              const float* __restrict__ v_edge,
                                              unsigned short* __restrict__ w2, unsigned short* __restrict__ vhve_d) {
    int h = blockIdx.x;
    int tid = threadIdx.x;
    for (int idx = tid; idx < 304*64; idx += 256) {
        int n = idx >> 6, kk = idx & 63;
        float val = 0.f;
        if (n < NHOP && kk < 32) val = q_hop[(size_t)n*DM + h*DH + kk];
        else if (n >= 264 && n < 264 + NEDGE) {
            int e = n - 264;
            val = (kk < 32) ? q_edge[(size_t)e*DM + h*DH + kk]
                            : k_edge[(size_t)e*DM + h*DH + (kk - 32)];
        }
        w2[((size_t)h*304 + n)*64 + kk] = (unsigned short)f2bs(val);
    }
    for (int idx = tid; idx < 32*320; idx += 256) {
        int d = idx / 320, kk = idx - d*320;
        float val = 0.f;
        if (kk < NHOP) val = v_hop[(size_t)kk*DM + h*DH + d];
        else if (kk >= 264 && kk < 264 + NEDGE) val = v_edge[(size_t)(kk-264)*DM + h*DH + d];
        vhve_d[((size_t)h*32 + d)*320 + kk] = (unsigned short)f2bs(val);
    }
}

// ---------------- k_kht2: kht[bh][m][j] = Kh[h][m][:] @ k_bf[bh][j][:]  via MFMA ----------------
__global__ __launch_bounds__(256) void k_kht2(const unsigned short* __restrict__ k_bf,
                                              const float* __restrict__ k_hop,
                                              unsigned short* __restrict__ kht) {
    int bh = blockIdx.x;
    int hh = bh & (NH-1);
    int r0 = blockIdx.y * 64;   // m tile
    int tid = threadIdx.x;
    int w = tid >> 6, l = tid & 63;
    int quad = l >> 4, lr = l & 15;

    int m = r0 + w*16 + lr;
    int mc = m < NHOP ? m : NHOP-1;
    const float* ar = k_hop + (size_t)mc*DM + hh*DH + quad*8;
    float4 a0 = *(const float4*)ar;
    float4 a1 = *(const float4*)(ar + 4);
    short8 af;
    af[0]=f2bs(a0.x); af[1]=f2bs(a0.y); af[2]=f2bs(a0.z); af[3]=f2bs(a0.w);
    af[4]=f2bs(a1.x); af[5]=f2bs(a1.y); af[6]=f2bs(a1.z); af[7]=f2bs(a1.w);

    for (int ct = 0; ct < 32; ++ct) {
        short8 bf = *(const short8*)(k_bf + ((size_t)bh*NN + ct*16 + lr)*DH + quad*8);
        f32x4 acc = (f32x4){0.f,0.f,0.f,0.f};
        acc = __builtin_amdgcn_mfma_f32_16x16x32_bf16(af, bf, acc, 0, 0, 0);
        #pragma unroll
        for (int reg = 0; reg < 4; ++reg) {
            int m2 = r0 + w*16 + quad*4 + reg;
            if (m2 < NHOP)
                kht[((size_t)bh*NHOP + m2)*NN + ct*16 + lr] = (unsigned short)f2bs(acc[reg]);
        }
    }
}

// ---------------- k_qhe2: qhe rows via MFMA; A = [q_bf | k_bf] (K=64), B^T = w2 ----------------
__global__ __launch_bounds__(256) void k_qhe2(const unsigned short* __restrict__ q_bf,
                                              const unsigned short* __restrict__ k_bf,
                                              const unsigned short* __restrict__ w2,
                                              unsigned short* __restrict__ qhe) {
    int bh = blockIdx.x;
    int hh = bh & (NH-1);
    int r0 = blockIdx.y * 64;
    int tid = threadIdx.x;
    int w = tid >> 6, l = tid & 63;
    int quad = l >> 4, lr = l & 15;

    int row0 = r0 + w*16 + lr;
    short8 af0 = *(const short8*)(q_bf + ((size_t)bh*NN + row0)*DH + quad*8);
    short8 af1 = *(const short8*)(k_bf + ((size_t)bh*NN + row0)*DH + quad*8);

    const unsigned short* w2h = w2 + (size_t)hh*304*64;
    for (int ct = 0; ct < 19; ++ct) {
        int col = ct*16 + lr;
        short8 b0 = *(const short8*)(w2h + (size_t)col*64 + quad*8);
        short8 b1 = *(const short8*)(w2h + (size_t)col*64 + 32 + quad*8);
        f32x4 acc = (f32x4){0.f,0.f,0.f,0.f};
        acc = __builtin_amdgcn_mfma_f32_16x16x32_bf16(af0, b0, acc, 0, 0, 0);
        acc = __builtin_amdgcn_mfma_f32_16x16x32_bf16(af1, b1, acc, 0, 0, 0);
        if (col < QHE_S) {
            #pragma unroll
            for (int reg = 0; reg < 4; ++reg) {
                int row = r0 + w*16 + quad*4 + reg;
                qhe[((size_t)bh*NN + row)*QHE_S + col] = (unsigned short)f2bs(acc[reg]);
            }
        }
    }
}

// ---------------- k_score: flash-style MFMA. block = (b, head, 16-row i-tile); 4 waves ----------------
// v5 (on v4's alias scheme): occupancy was proven NOT the constraint (r3: 33->43% occ, 0 speedup)
//     -> bottleneck is the scattered-gather address path (TA line-serialization). Remove 2 of the
//     3 global gathers per cell: stage this i-tile's 16 qhe rows (9.5KB) into LDS during phase A
//     (coalesced short8 copy, region aliases Pl - dead until after B3) and do the m/e bias
//     lookups as LDS reads. Only the irreducible kht gather stays global.
__global__ __launch_bounds__(256) void k_score(
    const unsigned short* __restrict__ q_bf, const unsigned short* __restrict__ k_bf,
    const unsigned short* __restrict__ vT_bf, const unsigned short* __restrict__ kht,
    const int* __restrict__ dist, const int* __restrict__ edge,
    const unsigned char* __restrict__ mask, unsigned short* __restrict__ qhe,
    float* __restrict__ ctx)
{
    int g = blockIdx.x;                 // 4096
    int r = g >> 3;                     // 0..511
    int b = (g & 7) + ((r >> 8) << 3);  // XCD-affine
    int rem = r & 255;
    int hh = rem >> 5;
    int i0 = (rem & 31) << 4;
    int bh = b*NH + hh;
    int tid = threadIdx.x;
    int w = tid >> 6, l = tid & 63;
    int lr = l & 15, quad = l >> 4;

    // LDS layout (35584 B):
    //   [0, 16384)      mje[16][512] u16      (phase A -> last read in scatter)
    //   [16384, 25856)  qh_lds[16][296] u16   (phase A -> phase C; aliases Pl's head)
    //   [16384, 33024)  Pl[16][520] u16       (P-write after B3 -> PV, intra-wave)
    //   [16384, 35072)  bins[16][292] f32     (aliases Pl; zero -> scatter -> dump, after PV)
    //   [0, 8192)       cpart[4][16][32] f32  (aliases mje; after scatter)
    //   [35072, 35584)  red[2][4][16] f32
    __shared__ __align__(16) unsigned char smem[35584];
    unsigned short (*mje)[512] = (unsigned short(*)[512])smem;
    unsigned short (*qh_lds)[296] = (unsigned short(*)[296])(smem + 16384);
    unsigned short (*Pl)[520] = (unsigned short(*)[520])(smem + 16384);
    float (*bins)[292] = (float(*)[292])(smem + 16384);
    float (*red)[4][16] = (float(*)[4][16])(smem + 35072);
    float* cpart = (float*)smem;

    // ---- phase A: decode dist/edge -> mje (coalesced int4); stage qhe i-rows -> qh_lds ----
    {
        const int4* dp = (const int4*)(dist + ((size_t)b*NN + i0)*NN);
        const int4* ep = (const int4*)(edge + ((size_t)b*NN + i0)*NN);
        unsigned short* mf = &mje[0][0];
        for (int idx = tid; idx < 2048; idx += 256) {
            int4 dv = dp[idx];
            int4 ev = ep[idx];
            int m0 = dv.x > 256 ? 256 : dv.x; if (dv.x < 0) m0 = 257;
            int m1 = dv.y > 256 ? 256 : dv.y; if (dv.y < 0) m1 = 257;
            int m2 = dv.z > 256 ? 256 : dv.z; if (dv.z < 0) m2 = 257;
            int m3 = dv.w > 256 ? 256 : dv.w; if (dv.w < 0) m3 = 257;
            int e0 = ev.x > 25 ? 25 : ev.x; if (ev.x < 0) e0 = 26;
            int e1 = ev.y > 25 ? 25 : ev.y; if (ev.y < 0) e1 = 26;
            int e2 = ev.z > 25 ? 25 : ev.z; if (ev.z < 0) e2 = 26;
            int e3 = ev.w > 25 ? 25 : ev.w; if (ev.w < 0) e3 = 26;
            uint2 pk;
            pk.x = (unsigned)(m0 | (e0<<9)) | ((unsigned)(m1 | (e1<<9)) << 16);
            pk.y = (unsigned)(m2 | (e2<<9)) | ((unsigned)(m3 | (e3<<9)) << 16);
            *(uint2*)&mf[idx*4] = pk;
        }
        // qhe rows i0..i0+15 are contiguous (stride QHE_S==296): 16*296 u16 = 592 short8
        const short8* s8 = (const short8*)(qhe + ((size_t)bh*NN + i0)*QHE_S);
        short8* d8 = (short8*)&qh_lds[0][0];
        for (int idx = tid; idx < 592; idx += 256) d8[idx] = s8[idx];
    }
    __syncthreads();   // B1: mje + qh_lds ready

    // ---- phase B: QK^T via MFMA (wave w covers j in [w*128, w*128+128)) ----
    int jbase = w*128;
    short8 af = *(const short8*)(q_bf + ((size_t)bh*NN + i0 + lr)*DH + quad*8);
    f32x4 sc[8];
    #pragma unroll
    for (int ct = 0; ct < 8; ++ct) {
        short8 bfr = *(const short8*)(k_bf + ((size_t)bh*NN + jbase + ct*16 + lr)*DH + quad*8);
        f32x4 z = (f32x4){0.f,0.f,0.f,0.f};
        sc[ct] = __builtin_amdgcn_mfma_f32_16x16x32_bf16(af, bfr, z, 0, 0, 0);
    }

    // ---- phase C: bias gathers + mask (kht from global; qh/qe from LDS) ----
    const unsigned short* khtb = kht + (size_t)bh*NHOP*NN;
    const unsigned char* mrow = mask + (size_t)b*NN;
    const float scale = 0.17677669529663687f;
    unsigned char msk[8];
    #pragma unroll
    for (int ct = 0; ct < 8; ++ct) msk[ct] = mrow[jbase + ct*16 + lr];

    #pragma unroll
    for (int ct = 0; ct < 8; ++ct) {
        int j = jbase + ct*16 + lr;
        #pragma unroll
        for (int reg = 0; reg < 4; ++reg) {
            int il = quad*4 + reg;
            int pk = mje[il][j];
            int m = pk & 511, e = pk >> 9;
            float a = sc[ct][reg] + bf2f(khtb[(size_t)m*NN + j])
                    + bf2f(qh_lds[il][m]) + bf2f(qh_lds[il][264 + e]);
            a *= scale;
            if (msk[ct]) a = -INFINITY;
            sc[ct][reg] = a;
        }
    }

    // ---- softmax across all 512 j (cross-wave via LDS) ----
    {
        float mymax[4];
        #pragma unroll
        for (int reg = 0; reg < 4; ++reg) {
            float mx = sc[0][reg];
            #pragma unroll
            for (int ct = 1; ct < 8; ++ct) mx = fmaxf(mx, sc[ct][reg]);
            #pragma unroll
            for (int o = 1; o < 16; o <<= 1) mx = fmaxf(mx, __shfl_xor(mx, o, 16));
            mymax[reg] = mx;
        }
        if (lr == 0) {
            #pragma unroll
            for (int reg = 0; reg < 4; ++reg) red[0][w][quad*4 + reg] = mymax[reg];
        }
        __syncthreads();   // B2: red[0] ready; all qh_lds reads done
        float mysum[4];
        #pragma unroll
        for (int reg = 0; reg < 4; ++reg) {
            int il = quad*4 + reg;
            float mx = fmaxf(fmaxf(red[0][0][il], red[0][1][il]), fmaxf(red[0][2][il], red[0][3][il]));
            float s = 0.f;
            #pragma unroll
            for (int ct = 0; ct < 8; ++ct) { float ex = __expf(sc[ct][reg] - mx); sc[ct][reg] = ex; s += ex; }
            #pragma unroll
            for (int o = 1; o < 16; o <<= 1) s += __shfl_xor(s, o, 16);
            mysum[reg] = s;
        }
        if (lr == 0) {
            #pragma unroll
            for (int reg = 0; reg < 4; ++reg) red[1][w][quad*4 + reg] = mysum[reg];
        }
        __syncthreads();   // B3: red[1] ready; qh_lds dead -> Pl may overwrite
        float inv_[4];
        #pragma unroll
        for (int reg = 0; reg < 4; ++reg) {
            int il = quad*4 + reg;
            inv_[reg] = 1.0f / (red[1][0][il] + red[1][1][il] + red[1][2][il] + red[1][3][il]);
        }
        // ---- P write only (normalize sc in place; bins scatter deferred until after PV) ----
        #pragma unroll
        for (int ct = 0; ct < 8; ++ct) {
            int j = jbase + ct*16 + lr;
            #pragma unroll
            for (int reg = 0; reg < 4; ++reg) {
                int il = quad*4 + reg;
                float ps = sc[ct][reg] * inv_[reg];
                sc[ct][reg] = ps;
                Pl[il][j] = (unsigned short)f2bs(ps);
            }
        }
    }

    // ---- PV via MFMA: wave w handles K-chunk [jbase, jbase+128) ----
    // Pl reads are intra-wave (this wave wrote exactly these rows/cols) -> no barrier needed.
    f32x4 acc0 = (f32x4){0.f,0.f,0.f,0.f};
    f32x4 acc1 = (f32x4){0.f,0.f,0.f,0.f};
    #pragma unroll
    for (int t = 0; t < 4; ++t) {
        int kk = jbase + t*32 + quad*8;
        short8 pa = *(const short8*)&Pl[lr][kk];
        short8 b0 = *(const short8*)(vT_bf + ((size_t)bh*DH + lr)*NN + kk);
        short8 b1 = *(const short8*)(vT_bf + ((size_t)bh*DH + 16 + lr)*NN + kk);
        acc0 = __builtin_amdgcn_mfma_f32_16x16x32_bf16(pa, b0, acc0, 0, 0, 0);
        acc1 = __builtin_amdgcn_mfma_f32_16x16x32_bf16(pa, b1, acc1, 0, 0, 0);
    }
    __syncthreads();   // B4: all waves done reading Pl -> bins may overwrite its region

    // ---- zero bins (aliases Pl) ----
    {
        float* bf_ = &bins[0][0];
        for (int idx = tid; idx < 16*292; idx += 256) bf_[idx] = 0.f;
    }
    __syncthreads();   // B5: bins zeroed

    // ---- bins scatter: pk re-read from mje; ps from sc ----
    #pragma unroll
    for (int ct = 0; ct < 8; ++ct) {
        int j = jbase + ct*16 + lr;
        #pragma unroll
        for (int reg = 0; reg < 4; ++reg) {
            int il = quad*4 + reg;
            int pk = mje[il][j];
            float ps = sc[ct][reg];
            atomicAdd(&bins[il][pk & 511], ps);
            atomicAdd(&bins[il][264 + (pk >> 9)], ps);
        }
    }
    __syncthreads();   // B6: bins complete; mje dead -> cpart alias safe

    // ---- dump bins -> qhe rows (vha, bf16) ----
    {
        int rowd = tid >> 4, c0 = tid & 15;
        unsigned short* dst = qhe + ((size_t)bh*NN + i0 + rowd)*QHE_S;
        for (int c = c0; c < 292; c += 16) dst[c] = (unsigned short)f2bs(bins[rowd][c]);
    }

    // ---- ctx partial reduce across waves (cpart aliases mje) ----
    #pragma unroll
    for (int reg = 0; reg < 4; ++reg) {
        int il = quad*4 + reg;
        cpart[((size_t)w*16 + il)*32 + lr]      = acc0[reg];
        cpart[((size_t)w*16 + il)*32 + 16 + lr] = acc1[reg];
    }
    __syncthreads();   // B7: cpart ready
    {
        int rowd = tid >> 4, dd = (tid & 15)*2;
        float v0 = 0.f, v1 = 0.f;
        #pragma unroll
        for (int ww = 0; ww < 4; ++ww) {
            v0 += cpart[((size_t)ww*16 + rowd)*32 + dd];
            v1 += cpart[((size_t)ww*16 + rowd)*32 + dd + 1];
        }
        float* cp = ctx + ((size_t)b*NN + i0 + rowd)*DM + hh*DH + dd;
        cp[0] = v0; cp[1] = v1;
    }
}

// ---------------- k_av2: ctx[b,i,h*32+d] += vha[bh,i,:] @ vhve_d[h][d][:]  via MFMA (K=320) ----------------
__global__ __launch_bounds__(256) void k_av2(const unsigned short* __restrict__ vha,
                                             const unsigned short* __restrict__ vhve_d,
                                             float* __restrict__ ctx) {
    int bh = blockIdx.x;
    int hh = bh & (NH-1);
    int b  = bh >> 3;
    int r0 = blockIdx.y * 64;
    int tid = threadIdx.x;
    int w = tid >> 6, l = tid & 63;
    int quad = l >> 4, lr = l & 15;

    const unsigned short* arow = vha + ((size_t)bh*NN + r0 + w*16 + lr)*QHE_S + quad*8;
    const unsigned short* br0  = vhve_d + ((size_t)hh*32 + lr)*320 + quad*8;
    const unsigned short* br1  = vhve_d + ((size_t)hh*32 + 16 + lr)*320 + quad*8;

    f32x4 acc0 = (f32x4){0.f,0.f,0.f,0.f};
    f32x4 acc1 = (f32x4){0.f,0.f,0.f,0.f};
    #pragma unroll
    for (int k0 = 0; k0 < 320; k0 += 32) {
        short8 af = *(const short8*)(arow + k0);
        short8 b0 = *(const short8*)(br0 + k0);
        short8 b1 = *(const short8*)(br1 + k0);
        acc0 = __builtin_amdgcn_mfma_f32_16x16x32_bf16(af, b0, acc0, 0, 0, 0);
        acc1 = __builtin_amdgcn_mfma_f32_16x16x32_bf16(af, b1, acc1, 0, 0, 0);
    }
    #pragma unroll
    for (int reg = 0; reg < 4; ++reg) {
        int row = r0 + w*16 + quad*4 + reg;
        float* cp = ctx + ((size_t)b*NN + row)*DM + hh*DH;
        cp[lr]      += acc0[reg];
        cp[16 + lr] += acc1[reg];
    }
}

extern "C" void kernel_launch(void* const* d_in, const int* in_sizes, int n_in,
                              void* d_out, int out_size, void* d_ws, size_t ws_size,
                              hipStream_t stream) {
    const float* x     = (const float*)d_in[0];
    const unsigned char* mask = (const unsigned char*)d_in[1];
    const int*   dist  = (const int*)d_in[2];
    const int*   edge  = (const int*)d_in[3];
    const float* node_W = (const float*)d_in[4];
    const float* node_b = (const float*)d_in[5];
    const float* ln1_g = (const float*)d_in[6];
    const float* ln1_b = (const float*)d_in[7];
    const float* Wq = (const float*)d_in[8];
    const float* bq = (const float*)d_in[9];
    const float* Wk = (const float*)d_in[10];
    const float* bk = (const float*)d_in[11];
    const float* Wv = (const float*)d_in[12];
    const float* bv = (const float*)d_in[13];
    const float* Wo = (const float*)d_in[14];
    const float* bo = (const float*)d_in[15];
    const float* ln2_g = (const float*)d_in[16];
    const float* ln2_b = (const float*)d_in[17];
    const float* W1 = (const float*)d_in[18];
    const float* b1 = (const float*)d_in[19];
    const float* W2 = (const float*)d_in[20];
    const float* b2 = (const float*)d_in[21];
    const float* q_hop  = (const float*)d_in[22];
    const float* q_edge = (const float*)d_in[23];
    const float* k_hop  = (const float*)d_in[24];
    const float* k_edge = (const float*)d_in[25];
    const float* v_hop  = (const float*)d_in[26];
    const float* v_edge = (const float*)d_in[27];
    const float* fln_g = (const float*)d_in[28];
    const float* fln_b = (const float*)d_in[29];
    const float* out_W = (const float*)d_in[30];
    const float* out_b = (const float*)d_in[31];
    float* out = (float*)d_out;

    float* ws = (float*)d_ws;
    float* h   = ws + 0;                          // 2,097,152
    float* y   = ws + 2097152;                    // 2,097,152
    unsigned short* q_bf  = (unsigned short*)(ws + 4194304);   // 2,097,152 ushorts
    unsigned short* k_bf  = (unsigned short*)(ws + 5242880);
    unsigned short* vT_bf = (unsigned short*)(ws + 6291456);   // [bh][d][n]
    float* ctx = ws + 7340032;                    // 2,097,152
    unsigned short* kht = (unsigned short*)(ws + 9437184);     // 128*258*512 ushorts (8,454,144 floats)
    float* ffn = ws + 9437184;                    // 8,388,608 floats (aliases kht, dead by then)
    unsigned short* qhe = (unsigned short*)(ws + 17891328);    // 128*512*296 ushorts; becomes vha
    // small tables alias y (y dead between qkv-GEMMs and ln2)
    unsigned short* w2     = (unsigned short*)(y);             // 8*304*64 ushorts
    unsigned short* vhve_d = (unsigned short*)(y + 81920);     // 8*32*320 ushorts

    k_mgemm<DIN, DM, 0, 0, 0><<<dim3(ROWS/64, DM/64), 256, 0, stream>>>(x, node_W, node_b, h);
    k_ln<<<ROWS/4, 256, 0, stream>>>(h, ln1_g, ln1_b, y);
    k_mgemm<DM, DM, 0, 0, 1><<<dim3(ROWS/64, DM/64), 256, 0, stream>>>(y, Wq, bq, q_bf);
    k_mgemm<DM, DM, 0, 0, 1><<<dim3(ROWS/64, DM/64), 256, 0, stream>>>(y, Wk, bk, k_bf);
    k_mgemm<DM, DM, 0, 0, 2><<<dim3(ROWS/64, DM/64), 256, 0, stream>>>(y, Wv, bv, vT_bf);
    // y now dead -> build fused tables
    k_prep<<<NH, 256, 0, stream>>>(q_hop, q_edge, k_edge, v_hop, v_edge, w2, vhve_d);
    k_kht2<<<dim3(BB*NH, 5), 256, 0, stream>>>(k_bf, k_hop, kht);
    k_qhe2<<<dim3(BB*NH, NN/64), 256, 0, stream>>>(q_bf, k_bf, w2, qhe);
    k_score<<<BB*NH*(NN/16), 256, 0, stream>>>(q_bf, k_bf, vT_bf, kht, dist, edge, mask, qhe, ctx);
    k_av2<<<dim3(BB*NH, NN/64), 256, 0, stream>>>(qhe, vhve_d, ctx);
    k_mgemm<DM, DM, 0, 1, 0><<<dim3(ROWS/64, DM/64), 256, 0, stream>>>(ctx, Wo, bo, h);
    k_ln<<<ROWS/4, 256, 0, stream>>>(h, ln2_g, ln2_b, y);
    k_mgemm<DM, FF, 1, 0, 0><<<dim3(ROWS/64, FF/64), 256, 0, stream>>>(y, W1, b1, ffn);
    k_mgemm<FF, DM, 0, 1, 0><<<dim3(ROWS/64, DM/64), 256, 0, stream>>>(ffn, W2, b2, h);
    k_ln<<<ROWS/4, 256, 0, stream>>>(h, fln_g, fln_b, y);
    k_mgemm<DM, DOUT, 0, 0, 0><<<dim3(ROWS/64, DOUT/64), 256, 0, stream>>>(y, out_W, out_b, out);
}